// Round 14
// baseline (172.570 us; speedup 1.0000x reference)
//
#include <hip/hip_runtime.h>
#include <hip/hip_bf16.h>

#define D_MODEL 1024
#define D_INNER 2048
#define D_STATE 16
#define DT_RANK 64
#define NB 2
#define LSEQ 1024
#define NROWS (NB * LSEQ)
#define XPN 96
#define NC 32
#define CL 32

typedef __attribute__((ext_vector_type(8))) short bf16x8;
typedef __attribute__((ext_vector_type(8))) unsigned short u16x8;
typedef __attribute__((ext_vector_type(4))) float f32x4;

__device__ __forceinline__ unsigned short f2bf(float x) {
    __hip_bfloat16 h = __float2bfloat16(x);
    return *reinterpret_cast<unsigned short*>(&h);
}
__device__ __forceinline__ float bf2f(unsigned short u) {
    unsigned int v = ((unsigned int)u) << 16;
    float f;
    __builtin_memcpy(&f, &v, 4);
    return f;
}
__device__ __forceinline__ unsigned short f2h(float x) {
    _Float16 h = (_Float16)x;
    unsigned short u;
    __builtin_memcpy(&u, &h, 2);
    return u;
}
__device__ __forceinline__ float h2f(unsigned short u) {
    _Float16 h;
    __builtin_memcpy(&h, &u, 2);
    return (float)h;
}

// ---------------- weight casts + LayerNorm in ONE dispatch ----------------
__global__ __launch_bounds__(256) void wcast_ln(const float* __restrict__ W0, unsigned short* __restrict__ D0,
                                                const float* __restrict__ W1, unsigned short* __restrict__ D1,
                                                const float* __restrict__ W2, unsigned short* __restrict__ D2,
                                                const float* __restrict__ W3, unsigned short* __restrict__ D3,
                                                const float* __restrict__ hx, const float* __restrict__ nw,
                                                const float* __restrict__ nb, unsigned short* __restrict__ lnout) {
    int bid = blockIdx.x;
    if (bid >= 6528) {
        int row = bid - 6528;
        const float4* xr = (const float4*)(hx + (size_t)row * D_MODEL);
        float4 v = xr[threadIdx.x];
        float s = v.x + v.y + v.z + v.w;
        float sq = v.x * v.x + v.y * v.y + v.z * v.z + v.w * v.w;
#pragma unroll
        for (int off = 32; off > 0; off >>= 1) {
            s += __shfl_down(s, off);
            sq += __shfl_down(sq, off);
        }
        __shared__ float ws[4], wq[4];
        __shared__ float smu, srstd;
        int wave = threadIdx.x >> 6;
        if ((threadIdx.x & 63) == 0) { ws[wave] = s; wq[wave] = sq; }
        __syncthreads();
        if (threadIdx.x == 0) {
            float ts = ws[0] + ws[1] + ws[2] + ws[3];
            float tq = wq[0] + wq[1] + wq[2] + wq[3];
            float mu = ts * (1.f / D_MODEL);
            float var = tq * (1.f / D_MODEL) - mu * mu;
            smu = mu;
            srstd = rsqrtf(var + 1e-5f);
        }
        __syncthreads();
        float mu = smu, rstd = srstd;
        float4 wv = ((const float4*)nw)[threadIdx.x];
        float4 bv = ((const float4*)nb)[threadIdx.x];
        ushort4 pk;
        pk.x = f2bf((v.x - mu) * rstd * wv.x + bv.x);
        pk.y = f2bf((v.y - mu) * rstd * wv.y + bv.y);
        pk.z = f2bf((v.z - mu) * rstd * wv.z + bv.z);
        pk.w = f2bf((v.w - mu) * rstd * wv.w + bv.w);
        *(ushort4*)(lnout + (size_t)row * D_MODEL + threadIdx.x * 4) = pk;
        return;
    }
    const float* W;
    unsigned short* Dst;
    int K, Nreal, bx, by;
    if (bid < 4096) { W = W0; Dst = D0; K = 1024; Nreal = 4096; bx = bid & 127; by = bid >> 7; }
    else if (bid < 4352) { int j = bid - 4096; W = W1; Dst = D1; K = 2048; Nreal = 96; bx = j & 3; by = j >> 2; }
    else if (bid < 6400) { int j = bid - 4352; W = W2; Dst = D2; K = 2048; Nreal = 1024; bx = j & 31; by = j >> 5; }
    else { int j = bid - 6400; W = W3; Dst = D3; K = 64; Nreal = 2048; bx = j & 63; by = j >> 6; }
    __shared__ float t[32][33];
    int tn = bx * 32, tk = by * 32;
    for (int e = threadIdx.x; e < 1024; e += 256) {
        int r = e >> 5, c = e & 31;
        int n = tn + c;
        t[r][c] = (n < Nreal) ? W[(size_t)(tk + r) * Nreal + n] : 0.f;
    }
    __syncthreads();
    for (int e = threadIdx.x; e < 1024; e += 256) {
        int r = e >> 5, c = e & 31;
        Dst[(size_t)(tn + r) * K + tk + c] = f2bf(t[c][r]);
    }
}

// ---------------- bf16 MFMA GEMM: C = A[M][K] @ Bt[N][K]^T ----------------
// 128x128 tile, BK=64, T2 source-pre-swizzle; plain raster block order.
// EPI 0: f32 C (+zoff). EPI 2: xz-split bf16. EPI 3: f16 partials (+zoff, Nreal guard).
// EPI 4: softplus(v+bias[col]) -> bf16 C2.
template <int EPI>
__global__ __launch_bounds__(256) void gemm_bf16(const unsigned short* __restrict__ A,
                                                 const unsigned short* __restrict__ Bt,
                                                 const float* __restrict__ bias,
                                                 float* __restrict__ C,
                                                 void* __restrict__ C2,
                                                 int M, int K, int ldc, int Nreal) {
    __shared__ unsigned short As[128 * 64];
    __shared__ unsigned short Bs[128 * 64];
    int bx = blockIdx.x, by = blockIdx.y;

    int tid = threadIdx.x;
    int lane = tid & 63;
    int wave = tid >> 6;
    int wr = (wave >> 1) * 64, wc = (wave & 1) * 64;
    int bm = by * 128, bn = bx * 128;
    int kchunk = K / gridDim.z;
    int kbeg = blockIdx.z * kchunk;

    f32x4 acc[4][4];
#pragma unroll
    for (int i = 0; i < 4; ++i)
#pragma unroll
        for (int j = 0; j < 4; ++j) acc[i][j] = (f32x4){0.f, 0.f, 0.f, 0.f};

    int ar = lane & 15;
    int kq = lane >> 4;

    for (int k0 = kbeg; k0 < kbeg + kchunk; k0 += 64) {
        __syncthreads();
#pragma unroll
        for (int s = 0; s < 4; ++s) {
            int seg = s * 256 + tid;
            int row = seg >> 3, p = seg & 7;
            int c = p ^ (row & 7);
            __builtin_amdgcn_global_load_lds(
                (const __attribute__((address_space(1))) void*)(A + (size_t)(bm + row) * K + k0 + c * 8),
                (__attribute__((address_space(3))) void*)(As + seg * 8), 16, 0, 0);
        }
#pragma unroll
        for (int s = 0; s < 4; ++s) {
            int seg = s * 256 + tid;
            int row = seg >> 3, p = seg & 7;
            int c = p ^ (row & 7);
            __builtin_amdgcn_global_load_lds(
                (const __attribute__((address_space(1))) void*)(Bt + (size_t)(bn + row) * K + k0 + c * 8),
                (__attribute__((address_space(3))) void*)(Bs + seg * 8), 16, 0, 0);
        }
        __syncthreads();
#pragma unroll
        for (int kk = 0; kk < 2; ++kk) {
            bf16x8 af[4], bfr[4];
#pragma unroll
            for (int i = 0; i < 4; ++i) {
                int row = wr + i * 16 + ar;
                int pos = ((kk << 2) | kq) ^ (row & 7);
                af[i] = *(const bf16x8*)&As[(size_t)row * 64 + pos * 8];
            }
#pragma unroll
            for (int j = 0; j < 4; ++j) {
                int row = wc + j * 16 + ar;
                int pos = ((kk << 2) | kq) ^ (row & 7);
                bfr[j] = *(const bf16x8*)&Bs[(size_t)row * 64 + pos * 8];
            }
#pragma unroll
            for (int i = 0; i < 4; ++i)
#pragma unroll
                for (int j = 0; j < 4; ++j)
                    acc[i][j] = __builtin_amdgcn_mfma_f32_16x16x32_bf16(af[i], bfr[j], acc[i][j], 0, 0, 0);
        }
    }

    int crow0 = bm + wr + (lane >> 4) * 4;
    int ccol0 = bn + wc + (lane & 15);
    size_t zoff = (size_t)blockIdx.z * (size_t)M * ldc;
#pragma unroll
    for (int i = 0; i < 4; ++i)
#pragma unroll
        for (int j = 0; j < 4; ++j) {
            int col = ccol0 + j * 16;
            if (EPI == 0) {
                if (col < Nreal) {
                    float* cp = C + zoff + (size_t)(crow0 + i * 16) * ldc + col;
#pragma unroll
                    for (int rr = 0; rr < 4; ++rr) cp[(size_t)rr * ldc] = acc[i][j][rr];
                }
            } else if (EPI == 2) {
                unsigned short* cx = (unsigned short*)C;
                unsigned short* cz = (unsigned short*)C2;
                if (col < 2048) {
#pragma unroll
                    for (int rr = 0; rr < 4; ++rr)
                        cx[(size_t)(crow0 + i * 16 + rr) * 2048 + col] = f2bf(acc[i][j][rr]);
                } else {
#pragma unroll
                    for (int rr = 0; rr < 4; ++rr)
                        cz[(size_t)(crow0 + i * 16 + rr) * 2048 + (col - 2048)] = f2bf(acc[i][j][rr]);
                }
            } else if (EPI == 3) {
                if (col < Nreal) {
                    unsigned short* cp = (unsigned short*)C2 + zoff + (size_t)(crow0 + i * 16) * ldc + col;
#pragma unroll
                    for (int rr = 0; rr < 4; ++rr) cp[(size_t)rr * ldc] = f2h(acc[i][j][rr]);
                }
            } else {  // EPI == 4
                float bv = bias[col];
                unsigned short* cp = (unsigned short*)C2 + (size_t)(crow0 + i * 16) * ldc + col;
#pragma unroll
                for (int rr = 0; rr < 4; ++rr) {
                    float v = acc[i][j][rr] + bv;
                    v = (v > 20.f) ? v : log1pf(__expf(v));
                    cp[(size_t)rr * ldc] = f2bf(v);
                }
            }
        }
}

// ---------------- split-K reduce for xp (KS=16, f16 partials) ----------------
__global__ __launch_bounds__(256) void reduce_xp(const unsigned short* __restrict__ part,
                                                 float* __restrict__ xp,
                                                 unsigned short* __restrict__ dtr) {
    int t = blockIdx.x * 256 + threadIdx.x;
    float s = 0.f;
#pragma unroll
    for (int k = 0; k < 16; ++k) s += h2f(part[(size_t)k * ((size_t)NROWS * XPN) + t]);
    int row = t / 96, col = t - row * 96;
    if (col < 64) dtr[(size_t)row * 64 + col] = f2bf(s);
    else xp[t] = s;
}

// ---------------- split-K reduce for out (KS=2, f16 partials) ----------------
__global__ __launch_bounds__(256) void reduce_out(const unsigned short* __restrict__ part,
                                                  float* __restrict__ out) {
    int t = blockIdx.x * 256 + threadIdx.x;
    const size_t stride = (size_t)NROWS * D_MODEL;
    ushort4 p0 = ((const ushort4*)part)[t];
    ushort4 p1 = ((const ushort4*)(part + stride))[t];
    float4 o;
    o.x = h2f(p0.x) + h2f(p1.x);
    o.y = h2f(p0.y) + h2f(p1.y);
    o.z = h2f(p0.z) + h2f(p1.z);
    o.w = h2f(p0.w) + h2f(p1.w);
    ((float4*)out)[t] = o;
}

// ---------------- causal depthwise conv (k=4) + SiLU, 8 channels/thread ----------------
__global__ __launch_bounds__(256) void conv_silu_kernel(const unsigned short* __restrict__ xx,
                                                        const float* __restrict__ cw,
                                                        const float* __restrict__ cb,
                                                        unsigned short* __restrict__ outb) {
    int gid = blockIdx.x * 256 + threadIdx.x;
    int d8 = (gid & 255) << 3;
    int bl = gid >> 8;
    int l = bl & (LSEQ - 1);
    const unsigned short* base = xx + (size_t)bl * D_INNER + d8;
    u16x8 zr = {0, 0, 0, 0, 0, 0, 0, 0};
    u16x8 X0 = *(const u16x8*)base;
    u16x8 X1 = (l >= 1) ? *(const u16x8*)(base - D_INNER) : zr;
    u16x8 X2 = (l >= 2) ? *(const u16x8*)(base - 2 * D_INNER) : zr;
    u16x8 X3 = (l >= 3) ? *(const u16x8*)(base - 3 * D_INNER) : zr;
    u16x8 ob;
#pragma unroll
    for (int e = 0; e < 8; ++e) {
        float4 we = *(const float4*)(cw + (size_t)(d8 + e) * 4);
        float acc = cb[d8 + e];
        acc = fmaf(we.w, bf2f(X0[e]), acc);
        acc = fmaf(we.z, bf2f(X1[e]), acc);
        acc = fmaf(we.y, bf2f(X2[e]), acc);
        acc = fmaf(we.x, bf2f(X3[e]), acc);
        ob[e] = f2bf(acc / (1.f + __expf(-acc)));
    }
    *(u16x8*)(outb + (size_t)bl * D_INNER + d8) = ob;
}

// ---------------- scan phase 1: per-chunk local scan (h0 = 0) ----------------
__global__ __launch_bounds__(256) void scan_local(const float* __restrict__ xp,
                                                  const unsigned short* __restrict__ delta,
                                                  const unsigned short* __restrict__ ub,
                                                  const float* __restrict__ A_log,
                                                  float* __restrict__ hst,
                                                  float* __restrict__ sdel) {
    int bc = blockIdx.x >> 3;
    int b = bc >> 5, c = bc & (NC - 1);
    int d = (blockIdx.x & 7) * 256 + threadIdx.x;
    int base_r = b * LSEQ + c * CL;
    __shared__ float Bsm[CL * 16];
    for (int e = threadIdx.x; e < CL * 4; e += 256) {
        int l = e >> 2, q4 = e & 3;
        float4 v = *(const float4*)&xp[(size_t)(base_r + l) * XPN + DT_RANK + q4 * 4];
        *(float4*)&Bsm[l * 16 + q4 * 4] = v;
    }
    __syncthreads();
    float Av[16];
    const float4* ap = (const float4*)(A_log + (size_t)d * 16);
#pragma unroll
    for (int qq = 0; qq < 4; ++qq) {
        float4 a = ap[qq];
        Av[4 * qq + 0] = -__expf(a.x); Av[4 * qq + 1] = -__expf(a.y);
        Av[4 * qq + 2] = -__expf(a.z); Av[4 * qq + 3] = -__expf(a.w);
    }
    float h[16] = {};
    float sd = 0.f;
    const unsigned short* dp = delta + (size_t)base_r * D_INNER + d;
    const unsigned short* up = ub + (size_t)base_r * D_INNER + d;
#pragma unroll 4
    for (int l = 0; l < CL; ++l) {
        float dv = bf2f(dp[(size_t)l * D_INNER]);
        float u = bf2f(up[(size_t)l * D_INNER]);
        float du = dv * u;
        sd += dv;
#pragma unroll
        for (int n = 0; n < 16; ++n) {
            float dA = __expf(dv * Av[n]);
            h[n] = fmaf(dA, h[n], du * Bsm[l * 16 + n]);
        }
    }
    size_t hi = ((size_t)(c * NB + b) * D_INNER + d) * 16;
#pragma unroll
    for (int qq = 0; qq < 4; ++qq) {
        float4 v = make_float4(h[4 * qq], h[4 * qq + 1], h[4 * qq + 2], h[4 * qq + 3]);
        *(float4*)(hst + hi + 4 * qq) = v;
    }
    sdel[(size_t)(c * NB + b) * D_INNER + d] = sd;
}

// ---------------- scan phase 2: cross-chunk combine (LDS-staged walk) ----------------
__global__ __launch_bounds__(256) void scan_combine(const float* __restrict__ A_log,
                                                    const float* __restrict__ sdel,
                                                    float* __restrict__ hst) {
    __shared__ float hl[NC][256];
    __shared__ float sl[NC][16];
    int b = blockIdx.x >> 7;
    int d0 = (blockIdx.x & 127) * 16;
    int t = threadIdx.x;
    int dd = t >> 4;
    for (int e = t; e < NC * 256; e += 256) {
        int c = e >> 8, tt = e & 255;
        hl[c][tt] = hst[(size_t)(c * NB + b) * (D_INNER * 16) + d0 * 16 + tt];
    }
    for (int e = t; e < NC * 16; e += 256) {
        int c = e >> 4, ddd = e & 15;
        sl[c][ddd] = sdel[(size_t)(c * NB + b) * D_INNER + d0 + ddd];
    }
    __syncthreads();
    float Avn = -__expf(A_log[(size_t)d0 * 16 + t]);
    float h = 0.f;
#pragma unroll
    for (int c = 0; c < NC; ++c) {
        float S = sl[c][dd];
        float tmp = hl[c][t];
        hl[c][t] = h;
        h = fmaf(__expf(Avn * S), h, tmp);
    }
    __syncthreads();
    for (int e = t; e < NC * 256; e += 256) {
        int c = e >> 8, tt = e & 255;
        hst[(size_t)(c * NB + b) * (D_INNER * 16) + d0 * 16 + tt] = hl[c][tt];
    }
}

// ---------------- scan phase 3: finalize, fuse silu(z) gate -> bf16 y ----------------
__global__ __launch_bounds__(256) void scan_final(const float* __restrict__ xp,
                                                  const unsigned short* __restrict__ delta,
                                                  const unsigned short* __restrict__ ub,
                                                  const unsigned short* __restrict__ zb,
                                                  const float* __restrict__ hst,
                                                  const float* __restrict__ A_log,
                                                  const float* __restrict__ Dp,
                                                  unsigned short* __restrict__ yb) {
    int bc = blockIdx.x >> 3;
    int b = bc >> 5, c = bc & (NC - 1);
    int d = (blockIdx.x & 7) * 256 + threadIdx.x;
    int base_r = b * LSEQ + c * CL;
    __shared__ float Bsm[CL * 16], Csm[CL * 16];
    for (int e = threadIdx.x; e < CL * 8; e += 256) {
        int l = e >> 3, q8 = e & 7;
        float4 v = *(const float4*)&xp[(size_t)(base_r + l) * XPN + DT_RANK + q8 * 4];
        if (q8 < 4) *(float4*)&Bsm[l * 16 + q8 * 4] = v;
        else *(float4*)&Csm[l * 16 + (q8 - 4) * 4] = v;
    }
    __syncthreads();
    float Av[16];
    const float4* ap = (const float4*)(A_log + (size_t)d * 16);
#pragma unroll
    for (int qq = 0; qq < 4; ++qq) {
        float4 a = ap[qq];
        Av[4 * qq + 0] = -__expf(a.x); Av[4 * qq + 1] = -__expf(a.y);
        Av[4 * qq + 2] = -__expf(a.z); Av[4 * qq + 3] = -__expf(a.w);
    }
    float h[16];
    size_t hi = ((size_t)(c * NB + b) * D_INNER + d) * 16;
#pragma unroll
    for (int qq = 0; qq < 4; ++qq) {
        float4 v = *(const float4*)(hst + hi + 4 * qq);
        h[4 * qq] = v.x; h[4 * qq + 1] = v.y; h[4 * qq + 2] = v.z; h[4 * qq + 3] = v.w;
    }
    float Dv = Dp[d];
    const unsigned short* dp = delta + (size_t)base_r * D_INNER + d;
    const unsigned short* up = ub + (size_t)base_r * D_INNER + d;
    const unsigned short* zp = zb + (size_t)base_r * D_INNER + d;
#pragma unroll 4
    for (int l = 0; l < CL; ++l) {
        float dv = bf2f(dp[(size_t)l * D_INNER]);
        float u = bf2f(up[(size_t)l * D_INNER]);
        float du = dv * u;
        float acc = 0.f;
#pragma unroll
        for (int n = 0; n < 16; ++n) {
            float dA = __expf(dv * Av[n]);
            h[n] = fmaf(dA, h[n], du * Bsm[l * 16 + n]);
            acc = fmaf(h[n], Csm[l * 16 + n], acc);
        }
        float yv = fmaf(u, Dv, acc);
        float zv = bf2f(zp[(size_t)l * D_INNER]);
        float sz = zv / (1.f + __expf(-zv));
        yb[(size_t)(base_r + l) * D_INNER + d] = f2bf(yv * sz);
    }
}

extern "C" void kernel_launch(void* const* d_in, const int* in_sizes, int n_in,
                              void* d_out, int out_size, void* d_ws, size_t ws_size,
                              hipStream_t stream) {
    const float* hidden = (const float*)d_in[0];
    const float* norm_w = (const float*)d_in[1];
    const float* norm_b = (const float*)d_in[2];
    const float* in_proj_w = (const float*)d_in[3];
    const float* conv_w = (const float*)d_in[4];
    const float* conv_b = (const float*)d_in[5];
    const float* x_proj_w = (const float*)d_in[6];
    const float* dt_proj_w = (const float*)d_in[7];
    const float* dt_proj_b = (const float*)d_in[8];
    const float* A_log = (const float*)d_in[9];
    const float* D_param = (const float*)d_in[10];
    const float* out_proj_w = (const float*)d_in[11];
    float* out = (float*)d_out;

    float* wsf = (float*)d_ws;
    unsigned short* hbufb = (unsigned short*)wsf;
    float* xpbuf = wsf;
    float* sdelbuf = wsf + 196608;
    unsigned short* xb = (unsigned short*)(wsf + 1048576);
    float* hst = wsf + 1048576;
    unsigned short* zb = (unsigned short*)(wsf + 3145728);
    unsigned short* ub = (unsigned short*)(wsf + 5242880);
    unsigned short* yb = ub;
    unsigned short* wAt = (unsigned short*)(wsf + 7340032);
    unsigned short* xpart16 = (unsigned short*)(wsf + 7340032);
    unsigned short* opart = (unsigned short*)(wsf + 7340032);
    unsigned short* wXt = (unsigned short*)(wsf + 10485760);
    unsigned short* wDt = (unsigned short*)(wsf + 10616832);
    unsigned short* dtrb = (unsigned short*)(wsf + 10682368);
    unsigned short* deltab = (unsigned short*)(wsf + 11665408);
    unsigned short* wOt = (unsigned short*)(wsf + 13762560);

    // 1. all weight casts + LayerNorm, one dispatch
    wcast_ln<<<6528 + NROWS, 256, 0, stream>>>(in_proj_w, wAt, x_proj_w, wXt, out_proj_w, wOt,
                                               dt_proj_w, wDt, hidden, norm_w, norm_b, hbufb);

    // 2. xz = h @ in_proj_w : x-half bf16 -> xb, z-half bf16 -> zb
    gemm_bf16<2><<<dim3(4096 / 128, NROWS / 128, 1), 256, 0, stream>>>(
        hbufb, wAt, nullptr, (float*)xb, zb, NROWS, 1024, 2048, 4096);

    // 3. conv + silu -> bf16 u (8 ch/thread)
    conv_silu_kernel<<<(NROWS * D_INNER) / 2048, 256, 0, stream>>>(xb, conv_w, conv_b, ub);

    // 4. xp partials = u @ x_proj_w (split-K = 16, f16 partials)
    gemm_bf16<3><<<dim3(1, NROWS / 128, 16), 256, 0, stream>>>(
        ub, wXt, nullptr, nullptr, xpart16, NROWS, 2048, XPN, XPN);

    // 5. reduce partials -> xp f32 (cols>=64) + dt_r bf16 (cols<64)
    reduce_xp<<<(NROWS * XPN) / 256, 256, 0, stream>>>(xpart16, xpbuf, dtrb);

    // 6. delta = softplus(dt_r @ dt_proj_w + b) -> bf16 (MFMA)
    gemm_bf16<4><<<dim3(D_INNER / 128, NROWS / 128, 1), 256, 0, stream>>>(
        dtrb, wDt, dt_proj_b, nullptr, deltab, NROWS, 64, D_INNER, D_INNER);

    // 7-9. chunked selective scan + fused gate -> bf16 y
    scan_local<<<NB * NC * (D_INNER / 256), 256, 0, stream>>>(
        xpbuf, deltab, ub, A_log, hst, sdelbuf);
    scan_combine<<<256, 256, 0, stream>>>(A_log, sdelbuf, hst);
    scan_final<<<NB * NC * (D_INNER / 256), 256, 0, stream>>>(
        xpbuf, deltab, ub, zb, hst, A_log, D_param, yb);

    // 10. out partials = y @ out_proj_w (split-K = 2, f16 partials)
    gemm_bf16<3><<<dim3(1024 / 128, NROWS / 128, 2), 256, 0, stream>>>(
        yb, wOt, nullptr, nullptr, opart, NROWS, 2048, 1024, 1024);

    // 11. reduce f16 partials -> d_out
    reduce_out<<<(NROWS * D_MODEL / 4) / 256, 256, 0, stream>>>(opart, out);
}

// Round 15
// 166.483 us; speedup vs baseline: 1.0366x; 1.0366x over previous
//
#include <hip/hip_runtime.h>
#include <hip/hip_bf16.h>

#define D_MODEL 1024
#define D_INNER 2048
#define D_STATE 16
#define DT_RANK 64
#define NB 2
#define LSEQ 1024
#define NROWS (NB * LSEQ)
#define XPN 96
#define NC 32
#define CL 32

typedef __attribute__((ext_vector_type(8))) short bf16x8;
typedef __attribute__((ext_vector_type(8))) unsigned short u16x8;
typedef __attribute__((ext_vector_type(4))) float f32x4;

__device__ __forceinline__ unsigned short f2bf(float x) {
    __hip_bfloat16 h = __float2bfloat16(x);
    return *reinterpret_cast<unsigned short*>(&h);
}
__device__ __forceinline__ float bf2f(unsigned short u) {
    unsigned int v = ((unsigned int)u) << 16;
    float f;
    __builtin_memcpy(&f, &v, 4);
    return f;
}
__device__ __forceinline__ unsigned short f2h(float x) {
    _Float16 h = (_Float16)x;
    unsigned short u;
    __builtin_memcpy(&u, &h, 2);
    return u;
}
__device__ __forceinline__ float h2f(unsigned short u) {
    _Float16 h;
    __builtin_memcpy(&h, &u, 2);
    return (float)h;
}

// ---------------- weight casts + LayerNorm in ONE dispatch ----------------
__global__ __launch_bounds__(256) void wcast_ln(const float* __restrict__ W0, unsigned short* __restrict__ D0,
                                                const float* __restrict__ W1, unsigned short* __restrict__ D1,
                                                const float* __restrict__ W2, unsigned short* __restrict__ D2,
                                                const float* __restrict__ W3, unsigned short* __restrict__ D3,
                                                const float* __restrict__ hx, const float* __restrict__ nw,
                                                const float* __restrict__ nb, unsigned short* __restrict__ lnout) {
    int bid = blockIdx.x;
    if (bid >= 6528) {
        int row = bid - 6528;
        const float4* xr = (const float4*)(hx + (size_t)row * D_MODEL);
        float4 v = xr[threadIdx.x];
        float s = v.x + v.y + v.z + v.w;
        float sq = v.x * v.x + v.y * v.y + v.z * v.z + v.w * v.w;
#pragma unroll
        for (int off = 32; off > 0; off >>= 1) {
            s += __shfl_down(s, off);
            sq += __shfl_down(sq, off);
        }
        __shared__ float ws[4], wq[4];
        __shared__ float smu, srstd;
        int wave = threadIdx.x >> 6;
        if ((threadIdx.x & 63) == 0) { ws[wave] = s; wq[wave] = sq; }
        __syncthreads();
        if (threadIdx.x == 0) {
            float ts = ws[0] + ws[1] + ws[2] + ws[3];
            float tq = wq[0] + wq[1] + wq[2] + wq[3];
            float mu = ts * (1.f / D_MODEL);
            float var = tq * (1.f / D_MODEL) - mu * mu;
            smu = mu;
            srstd = rsqrtf(var + 1e-5f);
        }
        __syncthreads();
        float mu = smu, rstd = srstd;
        float4 wv = ((const float4*)nw)[threadIdx.x];
        float4 bv = ((const float4*)nb)[threadIdx.x];
        ushort4 pk;
        pk.x = f2bf((v.x - mu) * rstd * wv.x + bv.x);
        pk.y = f2bf((v.y - mu) * rstd * wv.y + bv.y);
        pk.z = f2bf((v.z - mu) * rstd * wv.z + bv.z);
        pk.w = f2bf((v.w - mu) * rstd * wv.w + bv.w);
        *(ushort4*)(lnout + (size_t)row * D_MODEL + threadIdx.x * 4) = pk;
        return;
    }
    const float* W;
    unsigned short* Dst;
    int K, Nreal, bx, by;
    if (bid < 4096) { W = W0; Dst = D0; K = 1024; Nreal = 4096; bx = bid & 127; by = bid >> 7; }
    else if (bid < 4352) { int j = bid - 4096; W = W1; Dst = D1; K = 2048; Nreal = 96; bx = j & 3; by = j >> 2; }
    else if (bid < 6400) { int j = bid - 4352; W = W2; Dst = D2; K = 2048; Nreal = 1024; bx = j & 31; by = j >> 5; }
    else { int j = bid - 6400; W = W3; Dst = D3; K = 64; Nreal = 2048; bx = j & 63; by = j >> 6; }
    __shared__ float t[32][33];
    int tn = bx * 32, tk = by * 32;
    for (int e = threadIdx.x; e < 1024; e += 256) {
        int r = e >> 5, c = e & 31;
        int n = tn + c;
        t[r][c] = (n < Nreal) ? W[(size_t)(tk + r) * Nreal + n] : 0.f;
    }
    __syncthreads();
    for (int e = threadIdx.x; e < 1024; e += 256) {
        int r = e >> 5, c = e & 31;
        Dst[(size_t)(tn + r) * K + tk + c] = f2bf(t[c][r]);
    }
}

// ---------------- bf16 MFMA GEMM: C = A[M][K] @ Bt[N][K]^T ----------------
// 128x128 tile, BK=64, T2 source-pre-swizzle; plain raster block order.
// EPI 0: f32 C (+zoff). EPI 2: xz-split bf16. EPI 3: f16 partials (+zoff, Nreal guard).
// EPI 4: softplus(v+bias[col]) -> bf16 C2.
template <int EPI>
__global__ __launch_bounds__(256) void gemm_bf16(const unsigned short* __restrict__ A,
                                                 const unsigned short* __restrict__ Bt,
                                                 const float* __restrict__ bias,
                                                 float* __restrict__ C,
                                                 void* __restrict__ C2,
                                                 int M, int K, int ldc, int Nreal) {
    __shared__ unsigned short As[128 * 64];
    __shared__ unsigned short Bs[128 * 64];
    int bx = blockIdx.x, by = blockIdx.y;

    int tid = threadIdx.x;
    int lane = tid & 63;
    int wave = tid >> 6;
    int wr = (wave >> 1) * 64, wc = (wave & 1) * 64;
    int bm = by * 128, bn = bx * 128;
    int kchunk = K / gridDim.z;
    int kbeg = blockIdx.z * kchunk;

    f32x4 acc[4][4];
#pragma unroll
    for (int i = 0; i < 4; ++i)
#pragma unroll
        for (int j = 0; j < 4; ++j) acc[i][j] = (f32x4){0.f, 0.f, 0.f, 0.f};

    int ar = lane & 15;
    int kq = lane >> 4;

    for (int k0 = kbeg; k0 < kbeg + kchunk; k0 += 64) {
        __syncthreads();
#pragma unroll
        for (int s = 0; s < 4; ++s) {
            int seg = s * 256 + tid;
            int row = seg >> 3, p = seg & 7;
            int c = p ^ (row & 7);
            __builtin_amdgcn_global_load_lds(
                (const __attribute__((address_space(1))) void*)(A + (size_t)(bm + row) * K + k0 + c * 8),
                (__attribute__((address_space(3))) void*)(As + seg * 8), 16, 0, 0);
        }
#pragma unroll
        for (int s = 0; s < 4; ++s) {
            int seg = s * 256 + tid;
            int row = seg >> 3, p = seg & 7;
            int c = p ^ (row & 7);
            __builtin_amdgcn_global_load_lds(
                (const __attribute__((address_space(1))) void*)(Bt + (size_t)(bn + row) * K + k0 + c * 8),
                (__attribute__((address_space(3))) void*)(Bs + seg * 8), 16, 0, 0);
        }
        __syncthreads();
#pragma unroll
        for (int kk = 0; kk < 2; ++kk) {
            bf16x8 af[4], bfr[4];
#pragma unroll
            for (int i = 0; i < 4; ++i) {
                int row = wr + i * 16 + ar;
                int pos = ((kk << 2) | kq) ^ (row & 7);
                af[i] = *(const bf16x8*)&As[(size_t)row * 64 + pos * 8];
            }
#pragma unroll
            for (int j = 0; j < 4; ++j) {
                int row = wc + j * 16 + ar;
                int pos = ((kk << 2) | kq) ^ (row & 7);
                bfr[j] = *(const bf16x8*)&Bs[(size_t)row * 64 + pos * 8];
            }
#pragma unroll
            for (int i = 0; i < 4; ++i)
#pragma unroll
                for (int j = 0; j < 4; ++j)
                    acc[i][j] = __builtin_amdgcn_mfma_f32_16x16x32_bf16(af[i], bfr[j], acc[i][j], 0, 0, 0);
        }
    }

    int crow0 = bm + wr + (lane >> 4) * 4;
    int ccol0 = bn + wc + (lane & 15);
    size_t zoff = (size_t)blockIdx.z * (size_t)M * ldc;
#pragma unroll
    for (int i = 0; i < 4; ++i)
#pragma unroll
        for (int j = 0; j < 4; ++j) {
            int col = ccol0 + j * 16;
            if (EPI == 0) {
                if (col < Nreal) {
                    float* cp = C + zoff + (size_t)(crow0 + i * 16) * ldc + col;
#pragma unroll
                    for (int rr = 0; rr < 4; ++rr) cp[(size_t)rr * ldc] = acc[i][j][rr];
                }
            } else if (EPI == 2) {
                unsigned short* cx = (unsigned short*)C;
                unsigned short* cz = (unsigned short*)C2;
                if (col < 2048) {
#pragma unroll
                    for (int rr = 0; rr < 4; ++rr)
                        cx[(size_t)(crow0 + i * 16 + rr) * 2048 + col] = f2bf(acc[i][j][rr]);
                } else {
#pragma unroll
                    for (int rr = 0; rr < 4; ++rr)
                        cz[(size_t)(crow0 + i * 16 + rr) * 2048 + (col - 2048)] = f2bf(acc[i][j][rr]);
                }
            } else if (EPI == 3) {
                if (col < Nreal) {
                    unsigned short* cp = (unsigned short*)C2 + zoff + (size_t)(crow0 + i * 16) * ldc + col;
#pragma unroll
                    for (int rr = 0; rr < 4; ++rr) cp[(size_t)rr * ldc] = f2h(acc[i][j][rr]);
                }
            } else {  // EPI == 4
                float bv = bias[col];
                unsigned short* cp = (unsigned short*)C2 + (size_t)(crow0 + i * 16) * ldc + col;
#pragma unroll
                for (int rr = 0; rr < 4; ++rr) {
                    float v = acc[i][j][rr] + bv;
                    v = (v > 20.f) ? v : log1pf(__expf(v));
                    cp[(size_t)rr * ldc] = f2bf(v);
                }
            }
        }
}

// ---------------- split-K reduce for xp (KS=16, f16 partials) ----------------
__global__ __launch_bounds__(256) void reduce_xp(const unsigned short* __restrict__ part,
                                                 float* __restrict__ xp,
                                                 unsigned short* __restrict__ dtr) {
    int t = blockIdx.x * 256 + threadIdx.x;
    float s = 0.f;
#pragma unroll
    for (int k = 0; k < 16; ++k) s += h2f(part[(size_t)k * ((size_t)NROWS * XPN) + t]);
    int row = t / 96, col = t - row * 96;
    if (col < 64) dtr[(size_t)row * 64 + col] = f2bf(s);
    else xp[t] = s;
}

// ---------------- split-K reduce for out (KS=4, f16 partials) ----------------
__global__ __launch_bounds__(256) void reduce_out(const unsigned short* __restrict__ part,
                                                  float* __restrict__ out) {
    int t = blockIdx.x * 256 + threadIdx.x;
    const size_t stride = (size_t)NROWS * D_MODEL;
    ushort4 p0 = ((const ushort4*)part)[t];
    ushort4 p1 = ((const ushort4*)(part + stride))[t];
    ushort4 p2 = ((const ushort4*)(part + 2 * stride))[t];
    ushort4 p3 = ((const ushort4*)(part + 3 * stride))[t];
    float4 o;
    o.x = h2f(p0.x) + h2f(p1.x) + h2f(p2.x) + h2f(p3.x);
    o.y = h2f(p0.y) + h2f(p1.y) + h2f(p2.y) + h2f(p3.y);
    o.z = h2f(p0.z) + h2f(p1.z) + h2f(p2.z) + h2f(p3.z);
    o.w = h2f(p0.w) + h2f(p1.w) + h2f(p2.w) + h2f(p3.w);
    ((float4*)out)[t] = o;
}

// ---------------- causal depthwise conv (k=4) + SiLU, 8 channels/thread ----------------
__global__ __launch_bounds__(256) void conv_silu_kernel(const unsigned short* __restrict__ xx,
                                                        const float* __restrict__ cw,
                                                        const float* __restrict__ cb,
                                                        unsigned short* __restrict__ outb) {
    int gid = blockIdx.x * 256 + threadIdx.x;
    int d8 = (gid & 255) << 3;
    int bl = gid >> 8;
    int l = bl & (LSEQ - 1);
    const unsigned short* base = xx + (size_t)bl * D_INNER + d8;
    u16x8 zr = {0, 0, 0, 0, 0, 0, 0, 0};
    u16x8 X0 = *(const u16x8*)base;
    u16x8 X1 = (l >= 1) ? *(const u16x8*)(base - D_INNER) : zr;
    u16x8 X2 = (l >= 2) ? *(const u16x8*)(base - 2 * D_INNER) : zr;
    u16x8 X3 = (l >= 3) ? *(const u16x8*)(base - 3 * D_INNER) : zr;
    u16x8 ob;
#pragma unroll
    for (int e = 0; e < 8; ++e) {
        float4 we = *(const float4*)(cw + (size_t)(d8 + e) * 4);
        float acc = cb[d8 + e];
        acc = fmaf(we.w, bf2f(X0[e]), acc);
        acc = fmaf(we.z, bf2f(X1[e]), acc);
        acc = fmaf(we.y, bf2f(X2[e]), acc);
        acc = fmaf(we.x, bf2f(X3[e]), acc);
        ob[e] = f2bf(acc / (1.f + __expf(-acc)));
    }
    *(u16x8*)(outb + (size_t)bl * D_INNER + d8) = ob;
}

// ---------------- scan phase 1: per-chunk local scan (h0 = 0) ----------------
__global__ __launch_bounds__(256) void scan_local(const float* __restrict__ xp,
                                                  const unsigned short* __restrict__ delta,
                                                  const unsigned short* __restrict__ ub,
                                                  const float* __restrict__ A_log,
                                                  float* __restrict__ hst,
                                                  float* __restrict__ sdel) {
    int bc = blockIdx.x >> 3;
    int b = bc >> 5, c = bc & (NC - 1);
    int d = (blockIdx.x & 7) * 256 + threadIdx.x;
    int base_r = b * LSEQ + c * CL;
    __shared__ float Bsm[CL * 16];
    for (int e = threadIdx.x; e < CL * 4; e += 256) {
        int l = e >> 2, q4 = e & 3;
        float4 v = *(const float4*)&xp[(size_t)(base_r + l) * XPN + DT_RANK + q4 * 4];
        *(float4*)&Bsm[l * 16 + q4 * 4] = v;
    }
    __syncthreads();
    float Av[16];
    const float4* ap = (const float4*)(A_log + (size_t)d * 16);
#pragma unroll
    for (int qq = 0; qq < 4; ++qq) {
        float4 a = ap[qq];
        Av[4 * qq + 0] = -__expf(a.x); Av[4 * qq + 1] = -__expf(a.y);
        Av[4 * qq + 2] = -__expf(a.z); Av[4 * qq + 3] = -__expf(a.w);
    }
    float h[16] = {};
    float sd = 0.f;
    const unsigned short* dp = delta + (size_t)base_r * D_INNER + d;
    const unsigned short* up = ub + (size_t)base_r * D_INNER + d;
#pragma unroll 4
    for (int l = 0; l < CL; ++l) {
        float dv = bf2f(dp[(size_t)l * D_INNER]);
        float u = bf2f(up[(size_t)l * D_INNER]);
        float du = dv * u;
        sd += dv;
#pragma unroll
        for (int n = 0; n < 16; ++n) {
            float dA = __expf(dv * Av[n]);
            h[n] = fmaf(dA, h[n], du * Bsm[l * 16 + n]);
        }
    }
    size_t hi = ((size_t)(c * NB + b) * D_INNER + d) * 16;
#pragma unroll
    for (int qq = 0; qq < 4; ++qq) {
        float4 v = make_float4(h[4 * qq], h[4 * qq + 1], h[4 * qq + 2], h[4 * qq + 3]);
        *(float4*)(hst + hi + 4 * qq) = v;
    }
    sdel[(size_t)(c * NB + b) * D_INNER + d] = sd;
}

// ---------------- scan phase 2: cross-chunk combine (LDS-staged walk) ----------------
__global__ __launch_bounds__(256) void scan_combine(const float* __restrict__ A_log,
                                                    const float* __restrict__ sdel,
                                                    float* __restrict__ hst) {
    __shared__ float hl[NC][256];
    __shared__ float sl[NC][16];
    int b = blockIdx.x >> 7;
    int d0 = (blockIdx.x & 127) * 16;
    int t = threadIdx.x;
    int dd = t >> 4;
    for (int e = t; e < NC * 256; e += 256) {
        int c = e >> 8, tt = e & 255;
        hl[c][tt] = hst[(size_t)(c * NB + b) * (D_INNER * 16) + d0 * 16 + tt];
    }
    for (int e = t; e < NC * 16; e += 256) {
        int c = e >> 4, ddd = e & 15;
        sl[c][ddd] = sdel[(size_t)(c * NB + b) * D_INNER + d0 + ddd];
    }
    __syncthreads();
    float Avn = -__expf(A_log[(size_t)d0 * 16 + t]);
    float h = 0.f;
#pragma unroll
    for (int c = 0; c < NC; ++c) {
        float S = sl[c][dd];
        float tmp = hl[c][t];
        hl[c][t] = h;
        h = fmaf(__expf(Avn * S), h, tmp);
    }
    __syncthreads();
    for (int e = t; e < NC * 256; e += 256) {
        int c = e >> 8, tt = e & 255;
        hst[(size_t)(c * NB + b) * (D_INNER * 16) + d0 * 16 + tt] = hl[c][tt];
    }
}

// ---------------- scan phase 3: finalize, fuse silu(z) gate -> bf16 y ----------------
__global__ __launch_bounds__(256) void scan_final(const float* __restrict__ xp,
                                                  const unsigned short* __restrict__ delta,
                                                  const unsigned short* __restrict__ ub,
                                                  const unsigned short* __restrict__ zb,
                                                  const float* __restrict__ hst,
                                                  const float* __restrict__ A_log,
                                                  const float* __restrict__ Dp,
                                                  unsigned short* __restrict__ yb) {
    int bc = blockIdx.x >> 3;
    int b = bc >> 5, c = bc & (NC - 1);
    int d = (blockIdx.x & 7) * 256 + threadIdx.x;
    int base_r = b * LSEQ + c * CL;
    __shared__ float Bsm[CL * 16], Csm[CL * 16];
    for (int e = threadIdx.x; e < CL * 8; e += 256) {
        int l = e >> 3, q8 = e & 7;
        float4 v = *(const float4*)&xp[(size_t)(base_r + l) * XPN + DT_RANK + q8 * 4];
        if (q8 < 4) *(float4*)&Bsm[l * 16 + q8 * 4] = v;
        else *(float4*)&Csm[l * 16 + (q8 - 4) * 4] = v;
    }
    __syncthreads();
    float Av[16];
    const float4* ap = (const float4*)(A_log + (size_t)d * 16);
#pragma unroll
    for (int qq = 0; qq < 4; ++qq) {
        float4 a = ap[qq];
        Av[4 * qq + 0] = -__expf(a.x); Av[4 * qq + 1] = -__expf(a.y);
        Av[4 * qq + 2] = -__expf(a.z); Av[4 * qq + 3] = -__expf(a.w);
    }
    float h[16];
    size_t hi = ((size_t)(c * NB + b) * D_INNER + d) * 16;
#pragma unroll
    for (int qq = 0; qq < 4; ++qq) {
        float4 v = *(const float4*)(hst + hi + 4 * qq);
        h[4 * qq] = v.x; h[4 * qq + 1] = v.y; h[4 * qq + 2] = v.z; h[4 * qq + 3] = v.w;
    }
    float Dv = Dp[d];
    const unsigned short* dp = delta + (size_t)base_r * D_INNER + d;
    const unsigned short* up = ub + (size_t)base_r * D_INNER + d;
    const unsigned short* zp = zb + (size_t)base_r * D_INNER + d;
#pragma unroll 4
    for (int l = 0; l < CL; ++l) {
        float dv = bf2f(dp[(size_t)l * D_INNER]);
        float u = bf2f(up[(size_t)l * D_INNER]);
        float du = dv * u;
        float acc = 0.f;
#pragma unroll
        for (int n = 0; n < 16; ++n) {
            float dA = __expf(dv * Av[n]);
            h[n] = fmaf(dA, h[n], du * Bsm[l * 16 + n]);
            acc = fmaf(h[n], Csm[l * 16 + n], acc);
        }
        float yv = fmaf(u, Dv, acc);
        float zv = bf2f(zp[(size_t)l * D_INNER]);
        float sz = zv / (1.f + __expf(-zv));
        yb[(size_t)(base_r + l) * D_INNER + d] = f2bf(yv * sz);
    }
}

extern "C" void kernel_launch(void* const* d_in, const int* in_sizes, int n_in,
                              void* d_out, int out_size, void* d_ws, size_t ws_size,
                              hipStream_t stream) {
    const float* hidden = (const float*)d_in[0];
    const float* norm_w = (const float*)d_in[1];
    const float* norm_b = (const float*)d_in[2];
    const float* in_proj_w = (const float*)d_in[3];
    const float* conv_w = (const float*)d_in[4];
    const float* conv_b = (const float*)d_in[5];
    const float* x_proj_w = (const float*)d_in[6];
    const float* dt_proj_w = (const float*)d_in[7];
    const float* dt_proj_b = (const float*)d_in[8];
    const float* A_log = (const float*)d_in[9];
    const float* D_param = (const float*)d_in[10];
    const float* out_proj_w = (const float*)d_in[11];
    float* out = (float*)d_out;

    float* wsf = (float*)d_ws;
    unsigned short* hbufb = (unsigned short*)wsf;
    float* xpbuf = wsf;
    float* sdelbuf = wsf + 196608;
    unsigned short* xb = (unsigned short*)(wsf + 1048576);
    float* hst = wsf + 1048576;
    unsigned short* zb = (unsigned short*)(wsf + 3145728);
    unsigned short* ub = (unsigned short*)(wsf + 5242880);
    unsigned short* yb = ub;
    unsigned short* wAt = (unsigned short*)(wsf + 7340032);
    unsigned short* xpart16 = (unsigned short*)(wsf + 7340032);
    unsigned short* opart = (unsigned short*)(wsf + 7340032);
    unsigned short* wXt = (unsigned short*)(wsf + 10485760);
    unsigned short* wDt = (unsigned short*)(wsf + 10616832);
    unsigned short* dtrb = (unsigned short*)(wsf + 10682368);
    unsigned short* deltab = (unsigned short*)(wsf + 11665408);
    unsigned short* wOt = (unsigned short*)(wsf + 13762560);

    // 1. all weight casts + LayerNorm, one dispatch
    wcast_ln<<<6528 + NROWS, 256, 0, stream>>>(in_proj_w, wAt, x_proj_w, wXt, out_proj_w, wOt,
                                               dt_proj_w, wDt, hidden, norm_w, norm_b, hbufb);

    // 2. xz = h @ in_proj_w : x-half bf16 -> xb, z-half bf16 -> zb
    gemm_bf16<2><<<dim3(4096 / 128, NROWS / 128, 1), 256, 0, stream>>>(
        hbufb, wAt, nullptr, (float*)xb, zb, NROWS, 1024, 2048, 4096);

    // 3. conv + silu -> bf16 u (8 ch/thread)
    conv_silu_kernel<<<(NROWS * D_INNER) / 2048, 256, 0, stream>>>(xb, conv_w, conv_b, ub);

    // 4. xp partials = u @ x_proj_w (split-K = 16, f16 partials)
    gemm_bf16<3><<<dim3(1, NROWS / 128, 16), 256, 0, stream>>>(
        ub, wXt, nullptr, nullptr, xpart16, NROWS, 2048, XPN, XPN);

    // 5. reduce partials -> xp f32 (cols>=64) + dt_r bf16 (cols<64)
    reduce_xp<<<(NROWS * XPN) / 256, 256, 0, stream>>>(xpart16, xpbuf, dtrb);

    // 6. delta = softplus(dt_r @ dt_proj_w + b) -> bf16 (MFMA)
    gemm_bf16<4><<<dim3(D_INNER / 128, NROWS / 128, 1), 256, 0, stream>>>(
        dtrb, wDt, dt_proj_b, nullptr, deltab, NROWS, 64, D_INNER, D_INNER);

    // 7-9. chunked selective scan + fused gate -> bf16 y
    scan_local<<<NB * NC * (D_INNER / 256), 256, 0, stream>>>(
        xpbuf, deltab, ub, A_log, hst, sdelbuf);
    scan_combine<<<256, 256, 0, stream>>>(A_log, sdelbuf, hst);
    scan_final<<<NB * NC * (D_INNER / 256), 256, 0, stream>>>(
        xpbuf, deltab, ub, zb, hst, A_log, D_param, yb);

    // 10. out partials = y @ out_proj_w (split-K = 4, f16 partials)
    gemm_bf16<3><<<dim3(1024 / 128, NROWS / 128, 4), 256, 0, stream>>>(
        yb, wOt, nullptr, nullptr, opart, NROWS, 2048, 1024, 1024);

    // 11. reduce f16 partials -> d_out
    reduce_out<<<(NROWS * D_MODEL / 4) / 256, 256, 0, stream>>>(opart, out);
}